// Round 4
// baseline (536.462 us; speedup 1.0000x reference)
//
#include <hip/hip_runtime.h>
#include <math.h>

#define BB 16
#define CC 32
#define NN 300
#define TT 12
#define STF 40
#define DHD 16
#define COO 32
#define NCH 4
#define ALPHAF 0.05f

// workspace offsets (in floats)
#define OFF_STATES 0         // 76800
#define OFF_INP    76800     // 614400  [i][b][n][c]
#define OFF_XT     691200    // 1843200 [i][b][c*3+t][n]
#define OFF_GA1    2534400   // 76800 each
#define OFF_GB1    2611200
#define OFF_GA2    2688000
#define OFF_GB2    2764800
#define OFF_ADJ    2841600   // 1440000 [b][v][w]
#define OFF_H1     4281600   // 460800  [b][col][n]
// total 4742400 floats = 18.97 MB

__device__ __forceinline__ float sigf(float x){ return 1.0f/(1.0f+expf(-x)); }

// states[b][n][d] = st_node_fea[n] . W_s2d[:,d] + b_s2d[d]
__global__ void k_init_states(const float* __restrict__ st, const float* __restrict__ Ws,
                              const float* __restrict__ bs, float* __restrict__ states){
    int idx = blockIdx.x*256 + threadIdx.x;
    if (idx >= BB*NN*DHD) return;
    int d = idx & 15;
    int n = (idx >> 4) % NN;
    float acc = bs[d];
    const float* srow = st + n*STF;
    #pragma unroll
    for (int k=0;k<STF;k++) acc += srow[k]*Ws[k*DHD + d];
    states[idx] = acc;
}

// produces inp_all (chunk t-means) and x_t (transposed x for conv)
__global__ void k_prep(const float* __restrict__ x, float* __restrict__ x_t, float* __restrict__ inp){
    int idx = blockIdx.x*256 + threadIdx.x;   // (b,c,n), n fastest
    if (idx >= BB*CC*NN) return;
    int n = idx % NN;
    int c = (idx / NN) % CC;
    int b = idx / (NN*CC);
    const float* xp = x + ((b*CC + c)*NN + n)*TT;
    float v[TT];
    #pragma unroll
    for (int t=0;t<TT;t++) v[t] = xp[t];
    #pragma unroll
    for (int i=0;i<NCH;i++){
        float m = (v[3*i]+v[3*i+1]+v[3*i+2])*(1.0f/3.0f);
        inp[((i*BB + b)*NN + n)*CC + c] = m;
        #pragma unroll
        for (int t=0;t<3;t++)
            x_t[(((i*BB + b)*CC + c)*3 + t)*NN + n] = v[3*i+t];
    }
}

// one block (64 threads) per (b,n) row: GRU update + 4 edge projections
__global__ void k_gru(const float* __restrict__ inp_i, float* __restrict__ states,
                      const float* __restrict__ W_rz, const float* __restrict__ b_rz,
                      const float* __restrict__ W_h,  const float* __restrict__ b_h,
                      const float* __restrict__ Wc1,  const float* __restrict__ Wc2,
                      float* __restrict__ ga1, float* __restrict__ gb1,
                      float* __restrict__ ga2, float* __restrict__ gb2){
    int row = blockIdx.x;          // b*NN + n
    int tid = threadIdx.x;         // 0..63
    __shared__ float cat[48];
    __shared__ float r_s[16], z_s[16], hs_s[16];
    const float* ip = inp_i + row*CC;
    if (tid < CC) cat[tid] = ip[tid];
    else if (tid < 48) cat[tid] = states[row*DHD + (tid-32)];
    __syncthreads();
    if (tid < 32){
        float acc = b_rz[tid];
        #pragma unroll
        for (int k=0;k<48;k++) acc += cat[k]*W_rz[k*32 + tid];
        float s = sigf(acc);
        if (tid < 16) r_s[tid] = s; else z_s[tid-16] = s;
    }
    __syncthreads();
    if (tid < 16) cat[32+tid] *= r_s[tid];   // r * state
    __syncthreads();
    if (tid < 16){
        float acc = b_h[tid];
        #pragma unroll
        for (int k=0;k<48;k++) acc += cat[k]*W_h[k*DHD + tid];
        float h_ = tanhf(acc);
        float st = states[row*DHD + tid];
        float z  = z_s[tid];
        float ns = z*st + (1.0f-z)*h_;
        states[row*DHD + tid] = ns;
        hs_s[tid] = fmaxf(ns, 0.0f);
    }
    __syncthreads();
    int j = tid & 15, which = tid >> 4;
    const float* W = (which < 2) ? Wc1 : Wc2;
    int off = (which & 1) ? 16*DHD : 0;   // Wb rows 16..31
    float acc = 0.0f;
    #pragma unroll
    for (int k=0;k<16;k++) acc += hs_s[k]*W[off + k*DHD + j];
    float* dst = (which==0)? ga1 : (which==1)? gb1 : (which==2)? ga2 : gb2;
    dst[row*DHD + j] = acc;
}

#define AVT 8
__global__ void k_adj(const float* __restrict__ ga1, const float* __restrict__ gb1,
                      const float* __restrict__ ga2, const float* __restrict__ gb2,
                      const float* __restrict__ bfc2_1, const float* __restrict__ wfc1_1, const float* __restrict__ bfc1_1,
                      const float* __restrict__ bfc2_2, const float* __restrict__ wfc1_2, const float* __restrict__ bfc1_2,
                      float* __restrict__ adj){
    int b  = blockIdx.x / 38;
    int v0 = (blockIdx.x % 38) * AVT;
    int tid = threadIdx.x;  // 256
    __shared__ float a1[AVT][16], a2[AVT][16];
    __shared__ float w1[16], w2[16];
    if (tid < 16) w1[tid] = wfc1_1[tid];
    else if (tid < 32) w2[tid-16] = wfc1_2[tid-16];
    {
        int vl = tid >> 5, which = (tid >> 4) & 1, k = tid & 15;
        int v = v0 + vl;
        float val = 0.0f;
        if (v < NN)
            val = which ? (ga2[(b*NN+v)*DHD + k] + bfc2_2[k])
                        : (ga1[(b*NN+v)*DHD + k] + bfc2_1[k]);
        if (which) a2[vl][k] = val; else a1[vl][k] = val;
    }
    float B1 = bfc1_1[0], B2 = bfc1_2[0];
    __syncthreads();
    for (int w = tid; w < NN; w += 256){
        const float4* p1 = (const float4*)(gb1 + (b*NN + w)*DHD);
        const float4* p2 = (const float4*)(gb2 + (b*NN + w)*DHD);
        float4 A[4], Bv[4];
        #pragma unroll
        for (int q=0;q<4;q++){ A[q]=p1[q]; Bv[q]=p2[q]; }
        const float* g1 = (const float*)A;
        const float* g2 = (const float*)Bv;
        for (int vl=0; vl<AVT; vl++){
            if (v0+vl >= NN) break;
            float s = B1, m = B2;
            #pragma unroll
            for (int k=0;k<16;k++){
                s += fmaxf(a1[vl][k] + g1[k], 0.0f)*w1[k];
                m += fmaxf(a2[vl][k] + g2[k], 0.0f)*w2[k];
            }
            adj[(b*NN + v0+vl)*NN + w] = s * sigf(m);
        }
    }
}

#define CVT 16
#define NTILE 19  // ceil(300/16)

// hout[b][col][v] = ALPHA*xin + (1-ALPHA) * sum_w adj[b][v][w]*hin[b][col][w]
__global__ void k_conv(const float* __restrict__ adj, const float* __restrict__ hin,
                       const float* __restrict__ xin, float* __restrict__ hout){
    int b  = blockIdx.x / NTILE;
    int v0 = (blockIdx.x % NTILE) * CVT;
    int tid = threadIdx.x;  // 256
    __shared__ float adjs[CVT][304];
    const float* ap = adj + (b*NN + v0)*NN;
    int nv = min(CVT, NN - v0);
    for (int idx = tid; idx < CVT*NN; idx += 256){
        int vl = idx / NN, w = idx % NN;
        adjs[vl][w] = (vl < nv) ? ap[vl*NN + w] : 0.0f;
    }
    __syncthreads();
    int q = tid & 31, g = tid >> 5;   // g:0..7 -> rows {2g,2g+1}; cols q,q+32,q+64
    float acc[2][3] = {};
    const float* h0 = hin + b*96*NN;
    for (int w4 = 0; w4 < NN/4; w4++){
        float4 a0 = *(const float4*)&adjs[2*g  ][w4*4];
        float4 a1 = *(const float4*)&adjs[2*g+1][w4*4];
        #pragma unroll
        for (int j=0;j<3;j++){
            float4 h = *(const float4*)&h0[(q+32*j)*NN + w4*4];
            acc[0][j] += a0.x*h.x + a0.y*h.y + a0.z*h.z + a0.w*h.w;
            acc[1][j] += a1.x*h.x + a1.y*h.y + a1.z*h.z + a1.w*h.w;
        }
    }
    #pragma unroll
    for (int vi=0; vi<2; vi++){
        int v = v0 + 2*g + vi;
        if (v >= NN) continue;
        #pragma unroll
        for (int j=0;j<3;j++){
            int col = q + 32*j;
            hout[(b*96 + col)*NN + v] =
                ALPHAF*xin[(b*96 + col)*NN + v] + (1.0f-ALPHAF)*acc[vi][j];
        }
    }
}

// depth-2 conv fused with the output MLP
__global__ void k_conv_mlp(const float* __restrict__ adj, const float* __restrict__ hin,
                           const float* __restrict__ xin, const float* __restrict__ Wm,
                           const float* __restrict__ bmlp, float* __restrict__ out, int chunk){
    int b  = blockIdx.x / NTILE;
    int v0 = (blockIdx.x % NTILE) * CVT;
    int tid = threadIdx.x;  // 256
    __shared__ float adjs[CVT][304];
    __shared__ float hs[3][96][CVT];
    const float* ap = adj + (b*NN + v0)*NN;
    int nv = min(CVT, NN - v0);
    for (int idx = tid; idx < CVT*NN; idx += 256){
        int vl = idx / NN, w = idx % NN;
        adjs[vl][w] = (vl < nv) ? ap[vl*NN + w] : 0.0f;
    }
    __syncthreads();
    int q = tid & 31, g = tid >> 5;
    float acc[2][3] = {};
    const float* h1p = hin + b*96*NN;
    for (int w4 = 0; w4 < NN/4; w4++){
        float4 a0 = *(const float4*)&adjs[2*g  ][w4*4];
        float4 a1 = *(const float4*)&adjs[2*g+1][w4*4];
        #pragma unroll
        for (int j=0;j<3;j++){
            float4 h = *(const float4*)&h1p[(q+32*j)*NN + w4*4];
            acc[0][j] += a0.x*h.x + a0.y*h.y + a0.z*h.z + a0.w*h.w;
            acc[1][j] += a1.x*h.x + a1.y*h.y + a1.z*h.z + a1.w*h.w;
        }
    }
    // h2 tile into LDS
    #pragma unroll
    for (int vi=0; vi<2; vi++){
        int vl = 2*g + vi, v = v0 + vl;
        #pragma unroll
        for (int j=0;j<3;j++){
            int col = q + 32*j;
            float val = 0.0f;
            if (v < NN)
                val = ALPHAF*xin[(b*96 + col)*NN + v] + (1.0f-ALPHAF)*acc[vi][j];
            hs[2][col][vl] = val;
        }
    }
    // h0, h1 tiles
    for (int idx = tid; idx < 96*CVT; idx += 256){
        int col = idx / CVT, vl = idx % CVT;
        int v = v0 + vl;
        hs[0][col][vl] = (v < NN) ? xin[(b*96 + col)*NN + v] : 0.0f;
        hs[1][col][vl] = (v < NN) ? h1p[col*NN + v] : 0.0f;   // h1p already has b offset
    }
    __syncthreads();
    // MLP: out[b][o][v][chunk*3+t]
    for (int e = tid; e < COO*CVT*3; e += 256){
        int o  = e / (CVT*3);
        int r  = e % (CVT*3);
        int vl = r / 3, t = r % 3;
        int v = v0 + vl;
        if (v >= NN) continue;
        float acc2 = bmlp[o];
        #pragma unroll
        for (int c=0;c<CC;c++){
            int col = c*3 + t;
            acc2 += hs[0][col][vl]*Wm[c*COO + o]
                  + hs[1][col][vl]*Wm[(CC+c)*COO + o]
                  + hs[2][col][vl]*Wm[(2*CC+c)*COO + o];
        }
        out[((b*COO + o)*NN + v)*TT + chunk*3 + t] = acc2;
    }
}

extern "C" void kernel_launch(void* const* d_in, const int* in_sizes, int n_in,
                              void* d_out, int out_size, void* d_ws, size_t ws_size,
                              hipStream_t stream){
    const float* x     = (const float*)d_in[0];
    const float* stnf  = (const float*)d_in[1];
    const float* W_s2d = (const float*)d_in[2];
    const float* b_s2d = (const float*)d_in[3];
    const float* W_rz  = (const float*)d_in[4];
    const float* b_rz  = (const float*)d_in[5];
    const float* W_h   = (const float*)d_in[6];
    const float* b_h   = (const float*)d_in[7];
    const float* Wc1f2 = (const float*)d_in[8];
    const float* bc1f2 = (const float*)d_in[9];
    const float* Wc1f1 = (const float*)d_in[10];
    const float* bc1f1 = (const float*)d_in[11];
    const float* Wc2f2 = (const float*)d_in[12];
    const float* bc2f2 = (const float*)d_in[13];
    const float* Wc2f1 = (const float*)d_in[14];
    const float* bc2f1 = (const float*)d_in[15];
    const float* W_mlp = (const float*)d_in[16];
    const float* b_mlp = (const float*)d_in[17];
    float* out = (float*)d_out;
    float* ws  = (float*)d_ws;

    float* states = ws + OFF_STATES;
    float* inp    = ws + OFF_INP;
    float* xt     = ws + OFF_XT;
    float* ga1    = ws + OFF_GA1;
    float* gb1    = ws + OFF_GB1;
    float* ga2    = ws + OFF_GA2;
    float* gb2    = ws + OFF_GB2;
    float* adjb   = ws + OFF_ADJ;
    float* h1     = ws + OFF_H1;

    hipLaunchKernelGGL(k_init_states, dim3(300), dim3(256), 0, stream, stnf, W_s2d, b_s2d, states);
    hipLaunchKernelGGL(k_prep, dim3(600), dim3(256), 0, stream, x, xt, inp);

    for (int i=0;i<NCH;i++){
        const float* inp_i = inp + (size_t)i*BB*NN*CC;
        const float* xt_i  = xt  + (size_t)i*BB*96*NN;
        hipLaunchKernelGGL(k_gru, dim3(BB*NN), dim3(64), 0, stream,
                           inp_i, states, W_rz, b_rz, W_h, b_h, Wc1f2, Wc2f2,
                           ga1, gb1, ga2, gb2);
        hipLaunchKernelGGL(k_adj, dim3(BB*38), dim3(256), 0, stream,
                           ga1, gb1, ga2, gb2,
                           bc1f2, Wc1f1, bc1f1, bc2f2, Wc2f1, bc2f1, adjb);
        hipLaunchKernelGGL(k_conv, dim3(BB*NTILE), dim3(256), 0, stream,
                           adjb, xt_i, xt_i, h1);
        hipLaunchKernelGGL(k_conv_mlp, dim3(BB*NTILE), dim3(256), 0, stream,
                           adjb, h1, xt_i, W_mlp, b_mlp, out, i);
    }
}

// Round 6
// 380.601 us; speedup vs baseline: 1.4095x; 1.4095x over previous
//
#include <hip/hip_runtime.h>
#include <math.h>

#define BB 16
#define CC 32
#define NN 300
#define TT 12
#define STF 40
#define DHD 16
#define COO 32
#define NCH 4
#define ALPHAF 0.05f

// ---- batched workspace layout (floats), needs 45.5 MB ----
#define B_STATES 0          // 76800
#define B_INP    76800      // 614400   [i][b][n][c]
#define B_XT     691200     // 1843200  [i][b][col][n]
#define B_GA1    2534400    // 307200   [i][b][n][d]
#define B_GB1    2841600
#define B_GA2    3148800
#define B_GB2    3456000
#define B_ADJ    3763200    // 5760000  [i][b][v][w]
#define B_H1     9523200    // 1843200  [i][b][col][n]
#define B_TOTAL  11366400   // floats = 45,465,600 bytes

// ---- fallback per-chunk layout (floats), 18.97 MB (proven to fit) ----
#define F_STATES 0
#define F_INP    76800
#define F_XT     691200
#define F_GA1    2534400    // 76800 each
#define F_GB1    2611200
#define F_GA2    2688000
#define F_GB2    2764800
#define F_ADJ    2841600    // 1440000
#define F_H1     4281600    // 460800

__device__ __forceinline__ float sigf(float x){ return 1.0f/(1.0f+expf(-x)); }

__global__ void k_init_states(const float* __restrict__ st, const float* __restrict__ Ws,
                              const float* __restrict__ bs, float* __restrict__ states){
    int idx = blockIdx.x*256 + threadIdx.x;
    if (idx >= BB*NN*DHD) return;
    int d = idx & 15;
    int n = (idx >> 4) % NN;
    float acc = bs[d];
    const float* srow = st + n*STF;
    #pragma unroll
    for (int k=0;k<STF;k++) acc += srow[k]*Ws[k*DHD + d];
    states[idx] = acc;
}

__global__ void k_prep(const float* __restrict__ x, float* __restrict__ x_t, float* __restrict__ inp){
    int idx = blockIdx.x*256 + threadIdx.x;   // (b,c,n), n fastest
    if (idx >= BB*CC*NN) return;
    int n = idx % NN;
    int c = (idx / NN) % CC;
    int b = idx / (NN*CC);
    const float* xp = x + ((b*CC + c)*NN + n)*TT;
    float v[TT];
    #pragma unroll
    for (int t=0;t<TT;t++) v[t] = xp[t];
    #pragma unroll
    for (int i=0;i<NCH;i++){
        float m = (v[3*i]+v[3*i+1]+v[3*i+2])*(1.0f/3.0f);
        inp[((i*BB + b)*NN + n)*CC + c] = m;
        #pragma unroll
        for (int t=0;t<3;t++)
            x_t[(((i*BB + b)*CC + c)*3 + t)*NN + n] = v[3*i+t];
    }
}

// one block (64 threads) per (b,n) row: GRU update + 4 edge projections
__global__ void k_gru(const float* __restrict__ inp_i, float* __restrict__ states,
                      const float* __restrict__ W_rz, const float* __restrict__ b_rz,
                      const float* __restrict__ W_h,  const float* __restrict__ b_h,
                      const float* __restrict__ Wc1,  const float* __restrict__ Wc2,
                      float* __restrict__ ga1, float* __restrict__ gb1,
                      float* __restrict__ ga2, float* __restrict__ gb2){
    int row = blockIdx.x;          // b*NN + n
    int tid = threadIdx.x;         // 0..63
    __shared__ float cat[48];
    __shared__ float r_s[16], z_s[16], hs_s[16];
    const float* ip = inp_i + row*CC;
    if (tid < CC) cat[tid] = ip[tid];
    else if (tid < 48) cat[tid] = states[row*DHD + (tid-32)];
    __syncthreads();
    if (tid < 32){
        float acc = b_rz[tid];
        #pragma unroll
        for (int k=0;k<48;k++) acc += cat[k]*W_rz[k*32 + tid];
        float s = sigf(acc);
        if (tid < 16) r_s[tid] = s; else z_s[tid-16] = s;
    }
    __syncthreads();
    if (tid < 16) cat[32+tid] *= r_s[tid];   // r * state
    __syncthreads();
    if (tid < 16){
        float acc = b_h[tid];
        #pragma unroll
        for (int k=0;k<48;k++) acc += cat[k]*W_h[k*DHD + tid];
        float h_ = tanhf(acc);
        float st = states[row*DHD + tid];
        float z  = z_s[tid];
        float ns = z*st + (1.0f-z)*h_;
        states[row*DHD + tid] = ns;
        hs_s[tid] = fmaxf(ns, 0.0f);
    }
    __syncthreads();
    int j = tid & 15, which = tid >> 4;
    const float* W = (which < 2) ? Wc1 : Wc2;
    int off = (which & 1) ? 16*DHD : 0;
    float acc = 0.0f;
    #pragma unroll
    for (int k=0;k<16;k++) acc += hs_s[k]*W[off + k*DHD + j];
    float* dst = (which==0)? ga1 : (which==1)? gb1 : (which==2)? ga2 : gb2;
    dst[row*DHD + j] = acc;
}

#define AVT 8
// grid = nch*BB*38; ga/gb/adj are [nch][BB][...] contiguous
__global__ void k_adj(const float* __restrict__ ga1, const float* __restrict__ gb1,
                      const float* __restrict__ ga2, const float* __restrict__ gb2,
                      const float* __restrict__ bfc2_1, const float* __restrict__ wfc1_1, const float* __restrict__ bfc1_1,
                      const float* __restrict__ bfc2_2, const float* __restrict__ wfc1_2, const float* __restrict__ bfc1_2,
                      float* __restrict__ adj){
    int tile = blockIdx.x % 38;
    int ib   = blockIdx.x / 38;      // i*BB + b (or just b when nch==1)
    int v0 = tile * AVT;
    int tid = threadIdx.x;  // 256
    __shared__ float a1[AVT][16], a2[AVT][16];
    __shared__ float w1[16], w2[16];
    if (tid < 16) w1[tid] = wfc1_1[tid];
    else if (tid < 32) w2[tid-16] = wfc1_2[tid-16];
    {
        int vl = tid >> 5, which = (tid >> 4) & 1, k = tid & 15;
        int v = v0 + vl;
        float val = 0.0f;
        if (v < NN)
            val = which ? (ga2[(ib*NN+v)*DHD + k] + bfc2_2[k])
                        : (ga1[(ib*NN+v)*DHD + k] + bfc2_1[k]);
        if (which) a2[vl][k] = val; else a1[vl][k] = val;
    }
    float B1 = bfc1_1[0], B2 = bfc1_2[0];
    __syncthreads();
    for (int w = tid; w < NN; w += 256){
        const float4* p1 = (const float4*)(gb1 + (ib*NN + w)*DHD);
        const float4* p2 = (const float4*)(gb2 + (ib*NN + w)*DHD);
        float4 A[4], Bv[4];
        #pragma unroll
        for (int q=0;q<4;q++){ A[q]=p1[q]; Bv[q]=p2[q]; }
        const float* g1 = (const float*)A;
        const float* g2 = (const float*)Bv;
        for (int vl=0; vl<AVT; vl++){
            if (v0+vl >= NN) break;
            float s = B1, m = B2;
            #pragma unroll
            for (int k=0;k<16;k++){
                s += fmaxf(a1[vl][k] + g1[k], 0.0f)*w1[k];
                m += fmaxf(a2[vl][k] + g2[k], 0.0f)*w2[k];
            }
            adj[(ib*NN + v0+vl)*NN + w] = s * sigf(m);
        }
    }
}

#define CVT 16
#define NTILE 19  // ceil(300/16)

// grid = nch*BB*NTILE; hout[ib][col][v] = ALPHA*xin + (1-ALPHA)*sum_w adj[ib][v][w]*hin[ib][col][w]
__global__ void k_conv(const float* __restrict__ adj, const float* __restrict__ hin,
                       const float* __restrict__ xin, float* __restrict__ hout){
    int tile = blockIdx.x % NTILE;
    int ib   = blockIdx.x / NTILE;
    int v0 = tile * CVT;
    int tid = threadIdx.x;  // 256
    __shared__ float adjs[CVT][304];
    const float* ap = adj + (ib*NN + v0)*NN;
    int nv = min(CVT, NN - v0);
    for (int idx = tid; idx < CVT*NN; idx += 256){
        int vl = idx / NN, w = idx % NN;
        adjs[vl][w] = (vl < nv) ? ap[vl*NN + w] : 0.0f;
    }
    __syncthreads();
    int q = tid & 31, g = tid >> 5;   // rows {2g,2g+1}; cols q,q+32,q+64
    float acc[2][3] = {};
    const float* h0 = hin + ib*96*NN;
    for (int w4 = 0; w4 < NN/4; w4++){
        float4 a0 = *(const float4*)&adjs[2*g  ][w4*4];
        float4 a1 = *(const float4*)&adjs[2*g+1][w4*4];
        #pragma unroll
        for (int j=0;j<3;j++){
            float4 h = *(const float4*)&h0[(q+32*j)*NN + w4*4];
            acc[0][j] += a0.x*h.x + a0.y*h.y + a0.z*h.z + a0.w*h.w;
            acc[1][j] += a1.x*h.x + a1.y*h.y + a1.z*h.z + a1.w*h.w;
        }
    }
    #pragma unroll
    for (int vi=0; vi<2; vi++){
        int v = v0 + 2*g + vi;
        if (v >= NN) continue;
        #pragma unroll
        for (int j=0;j<3;j++){
            int col = q + 32*j;
            hout[(ib*96 + col)*NN + v] =
                ALPHAF*xin[(ib*96 + col)*NN + v] + (1.0f-ALPHAF)*acc[vi][j];
        }
    }
}

#define HP 17   // padded vl stride (odd -> col*HP mod 32 bijective, conflict-free)

// grid = nch*BB*NTILE; depth-2 conv fused with output MLP
__global__ void k_conv_mlp(const float* __restrict__ adj, const float* __restrict__ hin,
                           const float* __restrict__ xin, const float* __restrict__ Wm,
                           const float* __restrict__ bmlp, float* __restrict__ out, int chunk0){
    int tile = blockIdx.x % NTILE;
    int ib   = blockIdx.x / NTILE;
    int b    = ib % BB;
    int chunk = chunk0 + ib / BB;
    int v0 = tile * CVT;
    int tid = threadIdx.x;  // 256
    __shared__ float adjs[CVT][304];
    __shared__ float hs[3][96][HP];
    const float* ap = adj + (ib*NN + v0)*NN;
    int nv = min(CVT, NN - v0);
    for (int idx = tid; idx < CVT*NN; idx += 256){
        int vl = idx / NN, w = idx % NN;
        adjs[vl][w] = (vl < nv) ? ap[vl*NN + w] : 0.0f;
    }
    __syncthreads();
    int q = tid & 31, g = tid >> 5;
    float acc[2][3] = {};
    const float* h1p = hin + ib*96*NN;
    const float* x1p = xin + ib*96*NN;
    for (int w4 = 0; w4 < NN/4; w4++){
        float4 a0 = *(const float4*)&adjs[2*g  ][w4*4];
        float4 a1 = *(const float4*)&adjs[2*g+1][w4*4];
        #pragma unroll
        for (int j=0;j<3;j++){
            float4 h = *(const float4*)&h1p[(q+32*j)*NN + w4*4];
            acc[0][j] += a0.x*h.x + a0.y*h.y + a0.z*h.z + a0.w*h.w;
            acc[1][j] += a1.x*h.x + a1.y*h.y + a1.z*h.z + a1.w*h.w;
        }
    }
    // h2 tile into LDS
    #pragma unroll
    for (int vi=0; vi<2; vi++){
        int vl = 2*g + vi, v = v0 + vl;
        #pragma unroll
        for (int j=0;j<3;j++){
            int col = q + 32*j;
            float val = 0.0f;
            if (v < NN)
                val = ALPHAF*x1p[col*NN + v] + (1.0f-ALPHAF)*acc[vi][j];
            hs[2][col][vl] = val;
        }
    }
    // h0, h1 tiles
    for (int idx = tid; idx < 96*CVT; idx += 256){
        int col = idx / CVT, vl = idx % CVT;
        int v = v0 + vl;
        hs[0][col][vl] = (v < NN) ? x1p[col*NN + v] : 0.0f;
        hs[1][col][vl] = (v < NN) ? h1p[col*NN + v] : 0.0f;
    }
    __syncthreads();
    // MLP: out[b][o][v][chunk*3+t]
    for (int e = tid; e < COO*CVT*3; e += 256){
        int o  = e / (CVT*3);
        int r  = e % (CVT*3);
        int vl = r / 3, t = r % 3;
        int v = v0 + vl;
        if (v >= NN) continue;
        float acc2 = bmlp[o];
        #pragma unroll
        for (int c=0;c<CC;c++){
            int col = c*3 + t;
            acc2 += hs[0][col][vl]*Wm[c*COO + o]
                  + hs[1][col][vl]*Wm[(CC+c)*COO + o]
                  + hs[2][col][vl]*Wm[(2*CC+c)*COO + o];
        }
        out[((b*COO + o)*NN + v)*TT + chunk*3 + t] = acc2;
    }
}

extern "C" void kernel_launch(void* const* d_in, const int* in_sizes, int n_in,
                              void* d_out, int out_size, void* d_ws, size_t ws_size,
                              hipStream_t stream){
    const float* x     = (const float*)d_in[0];
    const float* stnf  = (const float*)d_in[1];
    const float* W_s2d = (const float*)d_in[2];
    const float* b_s2d = (const float*)d_in[3];
    const float* W_rz  = (const float*)d_in[4];
    const float* b_rz  = (const float*)d_in[5];
    const float* W_h   = (const float*)d_in[6];
    const float* b_h   = (const float*)d_in[7];
    const float* Wc1f2 = (const float*)d_in[8];
    const float* bc1f2 = (const float*)d_in[9];
    const float* Wc1f1 = (const float*)d_in[10];
    const float* bc1f1 = (const float*)d_in[11];
    const float* Wc2f2 = (const float*)d_in[12];
    const float* bc2f2 = (const float*)d_in[13];
    const float* Wc2f1 = (const float*)d_in[14];
    const float* bc2f1 = (const float*)d_in[15];
    const float* W_mlp = (const float*)d_in[16];
    const float* b_mlp = (const float*)d_in[17];
    float* out = (float*)d_out;
    float* ws  = (float*)d_ws;

    if (ws_size >= (size_t)B_TOTAL * sizeof(float)){
        // -------- batched path: all chunks' adj/conv/mlp in single launches --------
        float* states = ws + B_STATES;
        float* inp    = ws + B_INP;
        float* xt     = ws + B_XT;
        float* ga1    = ws + B_GA1;
        float* gb1    = ws + B_GB1;
        float* ga2    = ws + B_GA2;
        float* gb2    = ws + B_GB2;
        float* adjb   = ws + B_ADJ;
        float* h1     = ws + B_H1;

        hipLaunchKernelGGL(k_init_states, dim3(300), dim3(256), 0, stream, stnf, W_s2d, b_s2d, states);
        hipLaunchKernelGGL(k_prep, dim3(600), dim3(256), 0, stream, x, xt, inp);

        for (int i=0;i<NCH;i++){
            const float* inp_i = inp + (size_t)i*BB*NN*CC;
            size_t go = (size_t)i*BB*NN*DHD;
            hipLaunchKernelGGL(k_gru, dim3(BB*NN), dim3(64), 0, stream,
                               inp_i, states, W_rz, b_rz, W_h, b_h, Wc1f2, Wc2f2,
                               ga1+go, gb1+go, ga2+go, gb2+go);
        }
        hipLaunchKernelGGL(k_adj, dim3(NCH*BB*38), dim3(256), 0, stream,
                           ga1, gb1, ga2, gb2,
                           bc1f2, Wc1f1, bc1f1, bc2f2, Wc2f1, bc2f1, adjb);
        hipLaunchKernelGGL(k_conv, dim3(NCH*BB*NTILE), dim3(256), 0, stream,
                           adjb, xt, xt, h1);
        hipLaunchKernelGGL(k_conv_mlp, dim3(NCH*BB*NTILE), dim3(256), 0, stream,
                           adjb, h1, xt, W_mlp, b_mlp, out, 0);
    } else {
        // -------- fallback per-chunk path (fits in 19 MB) --------
        float* states = ws + F_STATES;
        float* inp    = ws + F_INP;
        float* xt     = ws + F_XT;
        float* ga1    = ws + F_GA1;
        float* gb1    = ws + F_GB1;
        float* ga2    = ws + F_GA2;
        float* gb2    = ws + F_GB2;
        float* adjb   = ws + F_ADJ;
        float* h1     = ws + F_H1;

        hipLaunchKernelGGL(k_init_states, dim3(300), dim3(256), 0, stream, stnf, W_s2d, b_s2d, states);
        hipLaunchKernelGGL(k_prep, dim3(600), dim3(256), 0, stream, x, xt, inp);

        for (int i=0;i<NCH;i++){
            const float* inp_i = inp + (size_t)i*BB*NN*CC;
            const float* xt_i  = xt  + (size_t)i*BB*96*NN;
            hipLaunchKernelGGL(k_gru, dim3(BB*NN), dim3(64), 0, stream,
                               inp_i, states, W_rz, b_rz, W_h, b_h, Wc1f2, Wc2f2,
                               ga1, gb1, ga2, gb2);
            hipLaunchKernelGGL(k_adj, dim3(BB*38), dim3(256), 0, stream,
                               ga1, gb1, ga2, gb2,
                               bc1f2, Wc1f1, bc1f1, bc2f2, Wc2f1, bc2f1, adjb);
            hipLaunchKernelGGL(k_conv, dim3(BB*NTILE), dim3(256), 0, stream,
                               adjb, xt_i, xt_i, h1);
            hipLaunchKernelGGL(k_conv_mlp, dim3(BB*NTILE), dim3(256), 0, stream,
                               adjb, h1, xt_i, W_mlp, b_mlp, out, i);
        }
    }
}

// Round 7
// 297.427 us; speedup vs baseline: 1.8037x; 1.2796x over previous
//
#include <hip/hip_runtime.h>
#include <math.h>

#define BB 16
#define CC 32
#define NN 300
#define TT 12
#define STF 40
#define DHD 16
#define COO 32
#define NCH 4
#define COL 96
#define ALPHAF 0.05f

// ---- batched workspace layout (floats), 45.5 MB (proven to fit in round 6) ----
#define B_STATES 0          // 76800 (only used by fallback)
#define B_INP    76800      // 614400   [i][b][n][c]
#define B_XT     691200     // 1843200  [ib][n][col]   (col = c*3+t, fastest)
#define B_GA1    2534400    // 307200   [i][b][n][d]
#define B_GB1    2841600
#define B_GA2    3148800
#define B_GB2    3456000
#define B_ADJ    3763200    // 5760000  [ib][v][w]
#define B_H1     9523200    // 1843200  [ib][n][col]
#define B_TOTAL  11366400   // floats = 45,465,600 bytes

// ---- fallback per-chunk layout (floats), 18.97 MB ----
#define F_STATES 0
#define F_INP    76800
#define F_XT     691200
#define F_GA1    2534400    // 76800 each
#define F_GB1    2611200
#define F_GA2    2688000
#define F_GB2    2764800
#define F_ADJ    2841600    // 1440000
#define F_H1     4281600    // 460800

__device__ __forceinline__ float sigf(float x){ return 1.0f/(1.0f+expf(-x)); }

__global__ void k_init_states(const float* __restrict__ st, const float* __restrict__ Ws,
                              const float* __restrict__ bs, float* __restrict__ states){
    int idx = blockIdx.x*256 + threadIdx.x;
    if (idx >= BB*NN*DHD) return;
    int d = idx & 15;
    int n = (idx >> 4) % NN;
    float acc = bs[d];
    const float* srow = st + n*STF;
    #pragma unroll
    for (int k=0;k<STF;k++) acc += srow[k]*Ws[k*DHD + d];
    states[idx] = acc;
}

// x (B,C,N,T) -> inp[i][b][n][c] (t-means) and xt[ib][n][col] (col = c*3+t)
__global__ void k_prep(const float* __restrict__ x, float* __restrict__ x_t, float* __restrict__ inp){
    int idx = blockIdx.x*256 + threadIdx.x;   // (b,c,n), n fastest
    if (idx >= BB*CC*NN) return;
    int n = idx % NN;
    int c = (idx / NN) % CC;
    int b = idx / (NN*CC);
    const float* xp = x + ((b*CC + c)*NN + n)*TT;
    float v[TT];
    #pragma unroll
    for (int t=0;t<TT;t++) v[t] = xp[t];
    #pragma unroll
    for (int i=0;i<NCH;i++){
        float m = (v[3*i]+v[3*i+1]+v[3*i+2])*(1.0f/3.0f);
        inp[((i*BB + b)*NN + n)*CC + c] = m;
        #pragma unroll
        for (int t=0;t<3;t++)
            x_t[(((size_t)(i*BB + b)*NN + n))*COL + (c*3 + t)] = v[3*i+t];
    }
}

// fused: init state + all 4 GRU steps + edge projections. block per (b,n) row.
__global__ void k_gru_all(const float* __restrict__ stnf, const float* __restrict__ W_s2d,
                          const float* __restrict__ b_s2d, const float* __restrict__ inp,
                          const float* __restrict__ W_rz, const float* __restrict__ b_rz,
                          const float* __restrict__ W_h,  const float* __restrict__ b_h,
                          const float* __restrict__ Wc1,  const float* __restrict__ Wc2,
                          float* __restrict__ ga1, float* __restrict__ gb1,
                          float* __restrict__ ga2, float* __restrict__ gb2){
    int row = blockIdx.x;          // b*NN + n
    int n   = row % NN;
    int tid = threadIdx.x;         // 0..63
    __shared__ float cat[48];
    __shared__ float r_s[16], z_s[16], hs_s[16], st_s[16];
    if (tid < 16){
        float acc = b_s2d[tid];
        const float* srow = stnf + n*STF;
        #pragma unroll
        for (int k=0;k<STF;k++) acc += srow[k]*W_s2d[k*DHD + tid];
        st_s[tid] = acc;
    }
    __syncthreads();
    for (int i=0;i<NCH;i++){
        const float* ip = inp + ((size_t)i*BB*NN + row)*CC;
        if (tid < CC) cat[tid] = ip[tid];
        else if (tid < 48) cat[tid] = st_s[tid-32];
        __syncthreads();
        if (tid < 32){
            float acc = b_rz[tid];
            #pragma unroll
            for (int k=0;k<48;k++) acc += cat[k]*W_rz[k*32 + tid];
            float s = sigf(acc);
            if (tid < 16) r_s[tid] = s; else z_s[tid-16] = s;
        }
        __syncthreads();
        if (tid < 16) cat[32+tid] = r_s[tid]*st_s[tid];
        __syncthreads();
        if (tid < 16){
            float acc = b_h[tid];
            #pragma unroll
            for (int k=0;k<48;k++) acc += cat[k]*W_h[k*DHD + tid];
            float h_ = tanhf(acc);
            float z  = z_s[tid];
            float ns = z*st_s[tid] + (1.0f-z)*h_;
            st_s[tid] = ns;
            hs_s[tid] = fmaxf(ns, 0.0f);
        }
        __syncthreads();
        int j = tid & 15, which = tid >> 4;
        const float* W = (which < 2) ? Wc1 : Wc2;
        int off = (which & 1) ? 16*DHD : 0;
        float acc = 0.0f;
        #pragma unroll
        for (int k=0;k<16;k++) acc += hs_s[k]*W[off + k*DHD + j];
        float* dst = (which==0)? ga1 : (which==1)? gb1 : (which==2)? ga2 : gb2;
        dst[((size_t)i*BB*NN + row)*DHD + j] = acc;
        __syncthreads();
    }
}

#define AVT 8
// grid = nch*BB*38
__global__ void k_adj(const float* __restrict__ ga1, const float* __restrict__ gb1,
                      const float* __restrict__ ga2, const float* __restrict__ gb2,
                      const float* __restrict__ bfc2_1, const float* __restrict__ wfc1_1, const float* __restrict__ bfc1_1,
                      const float* __restrict__ bfc2_2, const float* __restrict__ wfc1_2, const float* __restrict__ bfc1_2,
                      float* __restrict__ adj){
    int tile = blockIdx.x % 38;
    int ib   = blockIdx.x / 38;
    int v0 = tile * AVT;
    int tid = threadIdx.x;  // 256
    __shared__ float a1[AVT][16], a2[AVT][16];
    __shared__ float w1[16], w2[16];
    if (tid < 16) w1[tid] = wfc1_1[tid];
    else if (tid < 32) w2[tid-16] = wfc1_2[tid-16];
    {
        int vl = tid >> 5, which = (tid >> 4) & 1, k = tid & 15;
        int v = v0 + vl;
        float val = 0.0f;
        if (v < NN)
            val = which ? (ga2[((size_t)ib*NN+v)*DHD + k] + bfc2_2[k])
                        : (ga1[((size_t)ib*NN+v)*DHD + k] + bfc2_1[k]);
        if (which) a2[vl][k] = val; else a1[vl][k] = val;
    }
    float B1 = bfc1_1[0], B2 = bfc1_2[0];
    __syncthreads();
    for (int w = tid; w < NN; w += 256){
        const float4* p1 = (const float4*)(gb1 + ((size_t)ib*NN + w)*DHD);
        const float4* p2 = (const float4*)(gb2 + ((size_t)ib*NN + w)*DHD);
        float4 A[4], Bv[4];
        #pragma unroll
        for (int q=0;q<4;q++){ A[q]=p1[q]; Bv[q]=p2[q]; }
        const float* g1 = (const float*)A;
        const float* g2 = (const float*)Bv;
        for (int vl=0; vl<AVT; vl++){
            if (v0+vl >= NN) break;
            float s = B1, m = B2;
            #pragma unroll
            for (int k=0;k<16;k++){
                s += fmaxf(a1[vl][k] + g1[k], 0.0f)*w1[k];
                m += fmaxf(a2[vl][k] + g2[k], 0.0f)*w2[k];
            }
            adj[((size_t)ib*NN + v0+vl)*NN + w] = s * sigf(m);
        }
    }
}

#define CVT 16
#define NTILE 19  // ceil(300/16)

// grid = nch*BB*NTILE. hin/xin/hout layout [ib][n][col] -> coalesced reads.
__global__ void k_conv(const float* __restrict__ adj, const float* __restrict__ hin,
                       const float* __restrict__ xin, float* __restrict__ hout){
    int tile = blockIdx.x % NTILE;
    int ib   = blockIdx.x / NTILE;
    int v0 = tile * CVT;
    int tid = threadIdx.x;  // 256
    __shared__ float adjs[CVT][304];
    const float* ap = adj + ((size_t)ib*NN + v0)*NN;
    int nv = min(CVT, NN - v0);
    for (int idx = tid; idx < CVT*NN; idx += 256){
        int vl = idx / NN, w = idx % NN;
        adjs[vl][w] = (vl < nv) ? ap[vl*NN + w] : 0.0f;
    }
    __syncthreads();
    int q = tid & 31, g = tid >> 5;   // rows {2g,2g+1}; cols q,q+32,q+64
    float acc[2][3] = {};
    const float* H = hin + (size_t)ib*NN*COL;
    for (int w4 = 0; w4 < NN/4; w4++){
        float4 a0 = *(const float4*)&adjs[2*g  ][w4*4];
        float4 a1 = *(const float4*)&adjs[2*g+1][w4*4];
        const float* hr = H + (size_t)w4*4*COL;
        #pragma unroll
        for (int k=0;k<4;k++){
            float h0 = hr[k*COL + q];
            float h1 = hr[k*COL + q+32];
            float h2 = hr[k*COL + q+64];
            float a0k = ((const float*)&a0)[k];
            float a1k = ((const float*)&a1)[k];
            acc[0][0] += a0k*h0; acc[0][1] += a0k*h1; acc[0][2] += a0k*h2;
            acc[1][0] += a1k*h0; acc[1][1] += a1k*h1; acc[1][2] += a1k*h2;
        }
    }
    const float* X = xin + (size_t)ib*NN*COL;
    #pragma unroll
    for (int vi=0; vi<2; vi++){
        int v = v0 + 2*g + vi;
        if (v >= NN) continue;
        #pragma unroll
        for (int j=0;j<3;j++){
            int col = q + 32*j;
            hout[((size_t)ib*NN + v)*COL + col] =
                ALPHAF*X[(size_t)v*COL + col] + (1.0f-ALPHAF)*acc[vi][j];
        }
    }
}

#define HP 17   // padded vl stride

// grid = nch*BB*NTILE; depth-2 conv fused with output MLP
__global__ void k_conv_mlp(const float* __restrict__ adj, const float* __restrict__ hin,
                           const float* __restrict__ xin, const float* __restrict__ Wm,
                           const float* __restrict__ bmlp, float* __restrict__ out, int chunk0){
    int tile = blockIdx.x % NTILE;
    int ib   = blockIdx.x / NTILE;
    int b    = ib % BB;
    int chunk = chunk0 + ib / BB;
    int v0 = tile * CVT;
    int tid = threadIdx.x;  // 256
    __shared__ float adjs[CVT][304];
    __shared__ float hs[3][COL][HP];
    const float* ap = adj + ((size_t)ib*NN + v0)*NN;
    int nv = min(CVT, NN - v0);
    for (int idx = tid; idx < CVT*NN; idx += 256){
        int vl = idx / NN, w = idx % NN;
        adjs[vl][w] = (vl < nv) ? ap[vl*NN + w] : 0.0f;
    }
    __syncthreads();
    int q = tid & 31, g = tid >> 5;
    float acc[2][3] = {};
    const float* H = hin + (size_t)ib*NN*COL;
    const float* X = xin + (size_t)ib*NN*COL;
    for (int w4 = 0; w4 < NN/4; w4++){
        float4 a0 = *(const float4*)&adjs[2*g  ][w4*4];
        float4 a1 = *(const float4*)&adjs[2*g+1][w4*4];
        const float* hr = H + (size_t)w4*4*COL;
        #pragma unroll
        for (int k=0;k<4;k++){
            float h0 = hr[k*COL + q];
            float h1 = hr[k*COL + q+32];
            float h2 = hr[k*COL + q+64];
            float a0k = ((const float*)&a0)[k];
            float a1k = ((const float*)&a1)[k];
            acc[0][0] += a0k*h0; acc[0][1] += a0k*h1; acc[0][2] += a0k*h2;
            acc[1][0] += a1k*h0; acc[1][1] += a1k*h1; acc[1][2] += a1k*h2;
        }
    }
    // h2 tile into LDS
    #pragma unroll
    for (int vi=0; vi<2; vi++){
        int vl = 2*g + vi, v = v0 + vl;
        #pragma unroll
        for (int j=0;j<3;j++){
            int col = q + 32*j;
            float val = 0.0f;
            if (v < NN)
                val = ALPHAF*X[(size_t)v*COL + col] + (1.0f-ALPHAF)*acc[vi][j];
            hs[2][col][vl] = val;
        }
    }
    // h0, h1 tiles (coalesced: col fastest)
    for (int idx = tid; idx < COL*CVT; idx += 256){
        int vl = idx / COL, col = idx % COL;
        int v = v0 + vl;
        hs[0][col][vl] = (v < NN) ? X[(size_t)v*COL + col] : 0.0f;
        hs[1][col][vl] = (v < NN) ? H[(size_t)v*COL + col] : 0.0f;
    }
    __syncthreads();
    // MLP: out[b][o][v][chunk*3+t]
    for (int e = tid; e < COO*CVT*3; e += 256){
        int o  = e / (CVT*3);
        int r  = e % (CVT*3);
        int vl = r / 3, t = r % 3;
        int v = v0 + vl;
        if (v >= NN) continue;
        float acc2 = bmlp[o];
        #pragma unroll
        for (int c=0;c<CC;c++){
            int col = c*3 + t;
            acc2 += hs[0][col][vl]*Wm[c*COO + o]
                  + hs[1][col][vl]*Wm[(CC+c)*COO + o]
                  + hs[2][col][vl]*Wm[(2*CC+c)*COO + o];
        }
        out[(((size_t)b*COO + o)*NN + v)*TT + chunk*3 + t] = acc2;
    }
}

// old per-row single-step GRU (fallback path only)
__global__ void k_gru(const float* __restrict__ inp_i, float* __restrict__ states,
                      const float* __restrict__ W_rz, const float* __restrict__ b_rz,
                      const float* __restrict__ W_h,  const float* __restrict__ b_h,
                      const float* __restrict__ Wc1,  const float* __restrict__ Wc2,
                      float* __restrict__ ga1, float* __restrict__ gb1,
                      float* __restrict__ ga2, float* __restrict__ gb2){
    int row = blockIdx.x;
    int tid = threadIdx.x;
    __shared__ float cat[48];
    __shared__ float r_s[16], z_s[16], hs_s[16];
    const float* ip = inp_i + row*CC;
    if (tid < CC) cat[tid] = ip[tid];
    else if (tid < 48) cat[tid] = states[row*DHD + (tid-32)];
    __syncthreads();
    if (tid < 32){
        float acc = b_rz[tid];
        #pragma unroll
        for (int k=0;k<48;k++) acc += cat[k]*W_rz[k*32 + tid];
        float s = sigf(acc);
        if (tid < 16) r_s[tid] = s; else z_s[tid-16] = s;
    }
    __syncthreads();
    if (tid < 16) cat[32+tid] *= r_s[tid];
    __syncthreads();
    if (tid < 16){
        float acc = b_h[tid];
        #pragma unroll
        for (int k=0;k<48;k++) acc += cat[k]*W_h[k*DHD + tid];
        float h_ = tanhf(acc);
        float st = states[row*DHD + tid];
        float z  = z_s[tid];
        float ns = z*st + (1.0f-z)*h_;
        states[row*DHD + tid] = ns;
        hs_s[tid] = fmaxf(ns, 0.0f);
    }
    __syncthreads();
    int j = tid & 15, which = tid >> 4;
    const float* W = (which < 2) ? Wc1 : Wc2;
    int off = (which & 1) ? 16*DHD : 0;
    float acc = 0.0f;
    #pragma unroll
    for (int k=0;k<16;k++) acc += hs_s[k]*W[off + k*DHD + j];
    float* dst = (which==0)? ga1 : (which==1)? gb1 : (which==2)? ga2 : gb2;
    dst[row*DHD + j] = acc;
}

extern "C" void kernel_launch(void* const* d_in, const int* in_sizes, int n_in,
                              void* d_out, int out_size, void* d_ws, size_t ws_size,
                              hipStream_t stream){
    const float* x     = (const float*)d_in[0];
    const float* stnf  = (const float*)d_in[1];
    const float* W_s2d = (const float*)d_in[2];
    const float* b_s2d = (const float*)d_in[3];
    const float* W_rz  = (const float*)d_in[4];
    const float* b_rz  = (const float*)d_in[5];
    const float* W_h   = (const float*)d_in[6];
    const float* b_h   = (const float*)d_in[7];
    const float* Wc1f2 = (const float*)d_in[8];
    const float* bc1f2 = (const float*)d_in[9];
    const float* Wc1f1 = (const float*)d_in[10];
    const float* bc1f1 = (const float*)d_in[11];
    const float* Wc2f2 = (const float*)d_in[12];
    const float* bc2f2 = (const float*)d_in[13];
    const float* Wc2f1 = (const float*)d_in[14];
    const float* bc2f1 = (const float*)d_in[15];
    const float* W_mlp = (const float*)d_in[16];
    const float* b_mlp = (const float*)d_in[17];
    float* out = (float*)d_out;
    float* ws  = (float*)d_ws;

    if (ws_size >= (size_t)B_TOTAL * sizeof(float)){
        float* inp    = ws + B_INP;
        float* xt     = ws + B_XT;
        float* ga1    = ws + B_GA1;
        float* gb1    = ws + B_GB1;
        float* ga2    = ws + B_GA2;
        float* gb2    = ws + B_GB2;
        float* adjb   = ws + B_ADJ;
        float* h1     = ws + B_H1;

        hipLaunchKernelGGL(k_prep, dim3(600), dim3(256), 0, stream, x, xt, inp);
        hipLaunchKernelGGL(k_gru_all, dim3(BB*NN), dim3(64), 0, stream,
                           stnf, W_s2d, b_s2d, inp, W_rz, b_rz, W_h, b_h, Wc1f2, Wc2f2,
                           ga1, gb1, ga2, gb2);
        hipLaunchKernelGGL(k_adj, dim3(NCH*BB*38), dim3(256), 0, stream,
                           ga1, gb1, ga2, gb2,
                           bc1f2, Wc1f1, bc1f1, bc2f2, Wc2f1, bc2f1, adjb);
        hipLaunchKernelGGL(k_conv, dim3(NCH*BB*NTILE), dim3(256), 0, stream,
                           adjb, xt, xt, h1);
        hipLaunchKernelGGL(k_conv_mlp, dim3(NCH*BB*NTILE), dim3(256), 0, stream,
                           adjb, h1, xt, W_mlp, b_mlp, out, 0);
    } else {
        float* states = ws + F_STATES;
        float* inp    = ws + F_INP;
        float* xt     = ws + F_XT;
        float* ga1    = ws + F_GA1;
        float* gb1    = ws + F_GB1;
        float* ga2    = ws + F_GA2;
        float* gb2    = ws + F_GB2;
        float* adjb   = ws + F_ADJ;
        float* h1     = ws + F_H1;

        hipLaunchKernelGGL(k_init_states, dim3(300), dim3(256), 0, stream, stnf, W_s2d, b_s2d, states);
        hipLaunchKernelGGL(k_prep, dim3(600), dim3(256), 0, stream, x, xt, inp);

        for (int i=0;i<NCH;i++){
            const float* inp_i = inp + (size_t)i*BB*NN*CC;
            const float* xt_i  = xt  + (size_t)i*BB*NN*COL;
            hipLaunchKernelGGL(k_gru, dim3(BB*NN), dim3(64), 0, stream,
                               inp_i, states, W_rz, b_rz, W_h, b_h, Wc1f2, Wc2f2,
                               ga1, gb1, ga2, gb2);
            hipLaunchKernelGGL(k_adj, dim3(BB*38), dim3(256), 0, stream,
                               ga1, gb1, ga2, gb2,
                               bc1f2, Wc1f1, bc1f1, bc2f2, Wc2f1, bc2f1, adjb);
            hipLaunchKernelGGL(k_conv, dim3(BB*NTILE), dim3(256), 0, stream,
                               adjb, xt_i, xt_i, h1);
            hipLaunchKernelGGL(k_conv_mlp, dim3(BB*NTILE), dim3(256), 0, stream,
                               adjb, h1, xt_i, W_mlp, b_mlp, out, i);
        }
    }
}

// Round 8
// 254.970 us; speedup vs baseline: 2.1040x; 1.1665x over previous
//
#include <hip/hip_runtime.h>
#include <hip/hip_bf16.h>
#include <math.h>

#define BB 16
#define CC 32
#define NN 300
#define TT 12
#define STF 40
#define DHD 16
#define COO 32
#define NCH 4
#define COL 96
#define NIB 64          // NCH*BB
#define KP  320         // padded K / node dim
#define ALPHAF 0.05f

typedef __attribute__((ext_vector_type(8))) short short8;   // 8 bf16 (4 VGPRs)
typedef __attribute__((ext_vector_type(4))) float f32x4;    // MFMA 16x16 accumulator

// ---- workspace layout (float units), total 8,929,280 floats = 35.7 MB ----
// (ws proven >= 45.5 MB in round 6: batched path executed)
#define O_INP   0           // 614400   [i][b][n][c] fp32
#define O_XT    614400      // 1843200  [ib][n][col] fp32
#define O_GA1   2457600     // 307200 each, [ib][n][d] fp32
#define O_GB1   2764800
#define O_GA2   3072000
#define O_GB2   3379200
#define O_ADJB  3686400     // bf16 [ib][320][320] = 3276800 float-units
#define O_XTB   6963200     // bf16 [ib][96][320]  = 983040
#define O_H1B   7946240     // bf16 [ib][96][320]  = 983040

__device__ __forceinline__ float sigf(float x){ return 1.0f/(1.0f+expf(-x)); }

// x (B,C,N,T) -> inp[i][b][n][c] (t-means), xt[ib][n][col] fp32, xtb[ib][col][320] bf16
__global__ void k_prep(const float* __restrict__ x, float* __restrict__ xt,
                       __hip_bfloat16* __restrict__ xtb, float* __restrict__ inp){
    int idx = blockIdx.x*256 + threadIdx.x;   // (b,c,n), n fastest
    if (idx >= BB*CC*NN) return;
    int n = idx % NN;
    int c = (idx / NN) % CC;
    int b = idx / (NN*CC);
    const float* xp = x + ((b*CC + c)*NN + n)*TT;
    float v[TT];
    #pragma unroll
    for (int t=0;t<TT;t++) v[t] = xp[t];
    #pragma unroll
    for (int i=0;i<NCH;i++){
        float m = (v[3*i]+v[3*i+1]+v[3*i+2])*(1.0f/3.0f);
        int ib = i*BB + b;
        inp[((size_t)ib*NN + n)*CC + c] = m;
        #pragma unroll
        for (int t=0;t<3;t++){
            float val = v[3*i+t];
            int col = c*3 + t;
            xt [((size_t)ib*NN + n)*COL + col] = val;
            xtb[((size_t)ib*COL + col)*KP + n] = __float2bfloat16(val);
        }
    }
}

// fused: init state + all 4 GRU steps + edge projections. block per (b,n) row.
__global__ void k_gru_all(const float* __restrict__ stnf, const float* __restrict__ W_s2d,
                          const float* __restrict__ b_s2d, const float* __restrict__ inp,
                          const float* __restrict__ W_rz, const float* __restrict__ b_rz,
                          const float* __restrict__ W_h,  const float* __restrict__ b_h,
                          const float* __restrict__ Wc1,  const float* __restrict__ Wc2,
                          float* __restrict__ ga1, float* __restrict__ gb1,
                          float* __restrict__ ga2, float* __restrict__ gb2){
    int row = blockIdx.x;          // b*NN + n
    int n   = row % NN;
    int tid = threadIdx.x;         // 0..63
    __shared__ float cat[48];
    __shared__ float r_s[16], z_s[16], hs_s[16], st_s[16];
    if (tid < 16){
        float acc = b_s2d[tid];
        const float* srow = stnf + n*STF;
        #pragma unroll
        for (int k=0;k<STF;k++) acc += srow[k]*W_s2d[k*DHD + tid];
        st_s[tid] = acc;
    }
    __syncthreads();
    for (int i=0;i<NCH;i++){
        const float* ip = inp + ((size_t)i*BB*NN + row)*CC;
        if (tid < CC) cat[tid] = ip[tid];
        else if (tid < 48) cat[tid] = st_s[tid-32];
        __syncthreads();
        if (tid < 32){
            float acc = b_rz[tid];
            #pragma unroll
            for (int k=0;k<48;k++) acc += cat[k]*W_rz[k*32 + tid];
            float s = sigf(acc);
            if (tid < 16) r_s[tid] = s; else z_s[tid-16] = s;
        }
        __syncthreads();
        if (tid < 16) cat[32+tid] = r_s[tid]*st_s[tid];
        __syncthreads();
        if (tid < 16){
            float acc = b_h[tid];
            #pragma unroll
            for (int k=0;k<48;k++) acc += cat[k]*W_h[k*DHD + tid];
            float h_ = tanhf(acc);
            float z  = z_s[tid];
            float ns = z*st_s[tid] + (1.0f-z)*h_;
            st_s[tid] = ns;
            hs_s[tid] = fmaxf(ns, 0.0f);
        }
        __syncthreads();
        int j = tid & 15, which = tid >> 4;
        const float* W = (which < 2) ? Wc1 : Wc2;
        int off = (which & 1) ? 16*DHD : 0;
        float acc = 0.0f;
        #pragma unroll
        for (int k=0;k<16;k++) acc += hs_s[k]*W[off + k*DHD + j];
        float* dst = (which==0)? ga1 : (which==1)? gb1 : (which==2)? ga2 : gb2;
        dst[((size_t)i*BB*NN + row)*DHD + j] = acc;
        __syncthreads();
    }
}

#define AVT 8
// grid = NIB*38; adjb bf16 [ib][320][320], w in [300,320) zeroed (K-pad)
__global__ void k_adj(const float* __restrict__ ga1, const float* __restrict__ gb1,
                      const float* __restrict__ ga2, const float* __restrict__ gb2,
                      const float* __restrict__ bfc2_1, const float* __restrict__ wfc1_1, const float* __restrict__ bfc1_1,
                      const float* __restrict__ bfc2_2, const float* __restrict__ wfc1_2, const float* __restrict__ bfc1_2,
                      __hip_bfloat16* __restrict__ adjb){
    int tile = blockIdx.x % 38;
    int ib   = blockIdx.x / 38;
    int v0 = tile * AVT;
    int tid = threadIdx.x;  // 256
    __shared__ float a1[AVT][16], a2[AVT][16];
    __shared__ float w1[16], w2[16];
    if (tid < 16) w1[tid] = wfc1_1[tid];
    else if (tid < 32) w2[tid-16] = wfc1_2[tid-16];
    {
        int vl = tid >> 5, which = (tid >> 4) & 1, k = tid & 15;
        int v = v0 + vl;
        float val = 0.0f;
        if (v < NN)
            val = which ? (ga2[((size_t)ib*NN+v)*DHD + k] + bfc2_2[k])
                        : (ga1[((size_t)ib*NN+v)*DHD + k] + bfc2_1[k]);
        if (which) a2[vl][k] = val; else a1[vl][k] = val;
    }
    float B1 = bfc1_1[0], B2 = bfc1_2[0];
    __syncthreads();
    for (int w = tid; w < KP; w += 256){
        if (w < NN){
            const float4* p1 = (const float4*)(gb1 + ((size_t)ib*NN + w)*DHD);
            const float4* p2 = (const float4*)(gb2 + ((size_t)ib*NN + w)*DHD);
            float4 A[4], Bv[4];
            #pragma unroll
            for (int q=0;q<4;q++){ A[q]=p1[q]; Bv[q]=p2[q]; }
            const float* g1 = (const float*)A;
            const float* g2 = (const float*)Bv;
            for (int vl=0; vl<AVT; vl++){
                if (v0+vl >= NN) break;
                float s = B1, m = B2;
                #pragma unroll
                for (int k=0;k<16;k++){
                    s += fmaxf(a1[vl][k] + g1[k], 0.0f)*w1[k];
                    m += fmaxf(a2[vl][k] + g2[k], 0.0f)*w2[k];
                }
                adjb[((size_t)ib*KP + v0+vl)*KP + w] = __float2bfloat16(s * sigf(m));
            }
        } else {
            for (int vl=0; vl<AVT; vl++){
                if (v0+vl >= NN) break;
                adjb[((size_t)ib*KP + v0+vl)*KP + w] = __float2bfloat16(0.0f);
            }
        }
    }
}

// MFMA conv core: block = 4 waves, output tile 32 v-rows x 96 cols, K=320.
// wave (w&1): rows +0/+16 ; (w>>1): cols +0/+48. 3 accum tiles of 16x16 per wave.
// A: adjb[ib][v][k] (lane: row=l&15, k=8*(l>>4)+j) ; B: Hb[ib][col][k] (lane: col=l&15, same k)
// D: col=lane&15, row=(lane>>4)*4+reg (m89-verified)
__device__ __forceinline__ void conv_mfma_tile(const __hip_bfloat16* __restrict__ adjb,
                                               const __hip_bfloat16* __restrict__ Hb,
                                               int ib, int v0, int wave, int lane,
                                               f32x4& acc0, f32x4& acc1, f32x4& acc2){
    int l15 = lane & 15, lk = lane >> 4;
    int wrow = (wave & 1) * 16;
    int wcol = (wave >> 1) * 48;
    const short8* Ap  = (const short8*)(adjb + ((size_t)ib*KP + v0 + wrow + l15)*KP + 8*lk);
    const short8* Bp0 = (const short8*)(Hb   + ((size_t)ib*COL + wcol +  0 + l15)*KP + 8*lk);
    const short8* Bp1 = (const short8*)(Hb   + ((size_t)ib*COL + wcol + 16 + l15)*KP + 8*lk);
    const short8* Bp2 = (const short8*)(Hb   + ((size_t)ib*COL + wcol + 32 + l15)*KP + 8*lk);
    #pragma unroll 2
    for (int kk=0; kk<KP/32; kk++){
        short8 a = Ap[kk*4];                    // kk*4 short8 = 32 bf16 step
        acc0 = __builtin_amdgcn_mfma_f32_16x16x32_bf16(a, Bp0[kk*4], acc0, 0, 0, 0);
        acc1 = __builtin_amdgcn_mfma_f32_16x16x32_bf16(a, Bp1[kk*4], acc1, 0, 0, 0);
        acc2 = __builtin_amdgcn_mfma_f32_16x16x32_bf16(a, Bp2[kk*4], acc2, 0, 0, 0);
    }
}

// grid = NIB*10. h1 = 0.05*x + 0.95*(adj @ x); writes h1b bf16 [ib][col][320]
__global__ __launch_bounds__(256) void k_conv1(const __hip_bfloat16* __restrict__ adjb,
                                               const __hip_bfloat16* __restrict__ xtb,
                                               const float* __restrict__ xt,
                                               __hip_bfloat16* __restrict__ h1b){
    int ib = blockIdx.x / 10;
    int v0 = (blockIdx.x % 10) * 32;
    int tid = threadIdx.x;
    int wave = tid >> 6, lane = tid & 63;
    int l15 = lane & 15, lk = lane >> 4;
    int wrow = (wave & 1) * 16;
    int wcol = (wave >> 1) * 48;
    __shared__ float hbuf[COL][33];
    f32x4 acc0 = {0.f,0.f,0.f,0.f}, acc1 = acc0, acc2 = acc0;
    conv_mfma_tile(adjb, xtb, ib, v0, wave, lane, acc0, acc1, acc2);
    f32x4 accs[3] = {acc0, acc1, acc2};
    #pragma unroll
    for (int t=0;t<3;t++){
        int col = wcol + t*16 + l15;
        #pragma unroll
        for (int r=0;r<4;r++){
            int vloc = wrow + lk*4 + r;
            int v = v0 + vloc;
            float xval = (v < NN) ? xt[((size_t)ib*NN + v)*COL + col] : 0.0f;
            hbuf[col][vloc] = ALPHAF*xval + (1.0f-ALPHAF)*accs[t][r];
        }
    }
    __syncthreads();
    for (int idx = tid; idx < COL*32; idx += 256){
        int col = idx >> 5, vloc = idx & 31;
        int v = v0 + vloc;
        if (v < NN)
            h1b[((size_t)ib*COL + col)*KP + v] = __float2bfloat16(hbuf[col][vloc]);
    }
}

// grid = NIB*10. h2 = 0.05*x + 0.95*(adj @ h1), fused with output MLP.
__global__ __launch_bounds__(256) void k_conv2_mlp(const __hip_bfloat16* __restrict__ adjb,
                                                   const __hip_bfloat16* __restrict__ h1b,
                                                   const float* __restrict__ xt,
                                                   const float* __restrict__ Wm,
                                                   const float* __restrict__ bmlp,
                                                   float* __restrict__ out){
    int ib = blockIdx.x / 10;
    int v0 = (blockIdx.x % 10) * 32;
    int b  = ib % BB, chunk = ib / BB;
    int tid = threadIdx.x;
    int wave = tid >> 6, lane = tid & 63;
    int l15 = lane & 15, lk = lane >> 4;
    int wrow = (wave & 1) * 16;
    int wcol = (wave >> 1) * 48;
    __shared__ float hs[3][COL][33];
    f32x4 acc0 = {0.f,0.f,0.f,0.f}, acc1 = acc0, acc2 = acc0;
    conv_mfma_tile(adjb, h1b, ib, v0, wave, lane, acc0, acc1, acc2);
    f32x4 accs[3] = {acc0, acc1, acc2};
    // h2 tile
    #pragma unroll
    for (int t=0;t<3;t++){
        int col = wcol + t*16 + l15;
        #pragma unroll
        for (int r=0;r<4;r++){
            int vloc = wrow + lk*4 + r;
            int v = v0 + vloc;
            float xval = (v < NN) ? xt[((size_t)ib*NN + v)*COL + col] : 0.0f;
            hs[2][col][vloc] = ALPHAF*xval + (1.0f-ALPHAF)*accs[t][r];
        }
    }
    // h0 = x tile (coalesced along col)
    for (int idx = tid; idx < 32*COL; idx += 256){
        int vloc = idx / COL, col = idx % COL;
        int v = v0 + vloc;
        hs[0][col][vloc] = (v < NN) ? xt[((size_t)ib*NN + v)*COL + col] : 0.0f;
    }
    // h1 tile (coalesced along v)
    for (int idx = tid; idx < COL*32; idx += 256){
        int col = idx >> 5, vloc = idx & 31;
        int v = v0 + vloc;
        hs[1][col][vloc] = (v < NN) ? __bfloat162float(h1b[((size_t)ib*COL + col)*KP + v]) : 0.0f;
    }
    __syncthreads();
    // MLP: out[b][o][v][chunk*3+t]
    for (int e = tid; e < COO*32*3; e += 256){
        int o  = e / 96;
        int r  = e % 96;
        int vl = r / 3, t = r % 3;
        int v = v0 + vl;
        if (v >= NN) continue;
        float acc = bmlp[o];
        #pragma unroll
        for (int c=0;c<CC;c++){
            int col = c*3 + t;
            acc += hs[0][col][vl]*Wm[c*COO + o]
                 + hs[1][col][vl]*Wm[(CC+c)*COO + o]
                 + hs[2][col][vl]*Wm[(2*CC+c)*COO + o];
        }
        out[(((size_t)b*COO + o)*NN + v)*TT + chunk*3 + t] = acc;
    }
}

extern "C" void kernel_launch(void* const* d_in, const int* in_sizes, int n_in,
                              void* d_out, int out_size, void* d_ws, size_t ws_size,
                              hipStream_t stream){
    const float* x     = (const float*)d_in[0];
    const float* stnf  = (const float*)d_in[1];
    const float* W_s2d = (const float*)d_in[2];
    const float* b_s2d = (const float*)d_in[3];
    const float* W_rz  = (const float*)d_in[4];
    const float* b_rz  = (const float*)d_in[5];
    const float* W_h   = (const float*)d_in[6];
    const float* b_h   = (const float*)d_in[7];
    const float* Wc1f2 = (const float*)d_in[8];
    const float* bc1f2 = (const float*)d_in[9];
    const float* Wc1f1 = (const float*)d_in[10];
    const float* bc1f1 = (const float*)d_in[11];
    const float* Wc2f2 = (const float*)d_in[12];
    const float* bc2f2 = (const float*)d_in[13];
    const float* Wc2f1 = (const float*)d_in[14];
    const float* bc2f1 = (const float*)d_in[15];
    const float* W_mlp = (const float*)d_in[16];
    const float* b_mlp = (const float*)d_in[17];
    float* out = (float*)d_out;
    float* ws  = (float*)d_ws;

    float* inp = ws + O_INP;
    float* xt  = ws + O_XT;
    float* ga1 = ws + O_GA1;
    float* gb1 = ws + O_GB1;
    float* ga2 = ws + O_GA2;
    float* gb2 = ws + O_GB2;
    __hip_bfloat16* adjb = (__hip_bfloat16*)(ws + O_ADJB);
    __hip_bfloat16* xtb  = (__hip_bfloat16*)(ws + O_XTB);
    __hip_bfloat16* h1b  = (__hip_bfloat16*)(ws + O_H1B);

    hipLaunchKernelGGL(k_prep, dim3(600), dim3(256), 0, stream, x, xt, xtb, inp);
    hipLaunchKernelGGL(k_gru_all, dim3(BB*NN), dim3(64), 0, stream,
                       stnf, W_s2d, b_s2d, inp, W_rz, b_rz, W_h, b_h, Wc1f2, Wc2f2,
                       ga1, gb1, ga2, gb2);
    hipLaunchKernelGGL(k_adj, dim3(NIB*38), dim3(256), 0, stream,
                       ga1, gb1, ga2, gb2,
                       bc1f2, Wc1f1, bc1f1, bc2f2, Wc2f1, bc2f1, adjb);
    hipLaunchKernelGGL(k_conv1, dim3(NIB*10), dim3(256), 0, stream,
                       adjb, xtb, xt, h1b);
    hipLaunchKernelGGL(k_conv2_mlp, dim3(NIB*10), dim3(256), 0, stream,
                       adjb, h1b, xt, W_mlp, b_mlp, out);
}

// Round 12
// 223.504 us; speedup vs baseline: 2.4002x; 1.1408x over previous
//
#include <hip/hip_runtime.h>
#include <hip/hip_bf16.h>
#include <math.h>

#define BB 16
#define CC 32
#define NN 300
#define TT 12
#define STF 40
#define DHD 16
#define COO 32
#define NCH 4
#define COL 96
#define NIB 64          // NCH*BB
#define KP  320         // padded K / node dim
#define ALPHAF 0.05f
#define HS 40           // hst inner stride (halfwords): 80B, 16B-aligned, 2-way bank alias (free)

typedef __attribute__((ext_vector_type(8))) short short8;   // 8 bf16 (4 VGPRs)
typedef __attribute__((ext_vector_type(4))) float f32x4;    // MFMA 16x16 accumulator
typedef unsigned short ushort_t;

// ---- workspace layout (float units), total 8,930,816 floats = 35.7 MB (ws >= 45.5 MB proven) ----
#define O_INP   0           // 614400   [ib][n][c] fp32
#define O_XVB   614400      // 921600   bf16 [ib][300][96]  (A-side / epilogue x)
#define O_GA1   1536000     // 307200 each, [ib][n][d] fp32
#define O_GB1   1843200
#define O_GA2   2150400
#define O_GB2   2457600
#define O_ADJB  2764800     // bf16 [ib][320][320]
#define O_XTB   6041600     // bf16 [ib][96][320]  (B-side conv1)
#define O_H1B   7024640     // bf16 [ib][96][320]  (B-side conv2)
#define O_H1VB  8007680     // bf16 [ib][300][96]  (A-side MLP depth-1)
#define O_WMB   8929280     // bf16 [32][96]       (B-side MLP)

__device__ __forceinline__ float sigf(float x){ return 1.0f/(1.0f+expf(-x)); }

// x (B,C,N,T) -> inp (t-means), xtb [ib][col][320] bf16, xvb [ib][n][col] bf16
// + zero-fill K-pad of xtb/h1b + build Wmb
__global__ void k_prep(const float* __restrict__ x, __hip_bfloat16* __restrict__ xtb,
                       __hip_bfloat16* __restrict__ xvb, float* __restrict__ inp,
                       __hip_bfloat16* __restrict__ h1b, const float* __restrict__ Wm,
                       __hip_bfloat16* __restrict__ Wmb){
    int idx = blockIdx.x*256 + threadIdx.x;   // (b,c,n), n fastest
    if (idx >= BB*CC*NN) return;
    // side jobs on low threads
    if (idx < NIB*COL*(KP-NN)){               // 122880: zero K-pads
        int kk  = idx % (KP-NN);
        int col = (idx / (KP-NN)) % COL;
        int ib  = idx / ((KP-NN)*COL);
        size_t off = ((size_t)ib*COL + col)*KP + NN + kk;
        xtb[off] = __float2bfloat16(0.0f);
        h1b[off] = __float2bfloat16(0.0f);
    }
    if (idx < COO*COL){                       // 3072: Wmb[o][k] = Wm[k][o]
        int o = idx / COL, k = idx % COL;
        Wmb[o*COL + k] = __float2bfloat16(Wm[k*COO + o]);
    }
    int n = idx % NN;
    int c = (idx / NN) % CC;
    int b = idx / (NN*CC);
    const float* xp = x + ((b*CC + c)*NN + n)*TT;
    float v[TT];
    #pragma unroll
    for (int t=0;t<TT;t++) v[t] = xp[t];
    #pragma unroll
    for (int i=0;i<NCH;i++){
        float m = (v[3*i]+v[3*i+1]+v[3*i+2])*(1.0f/3.0f);
        int ib = i*BB + b;
        inp[((size_t)ib*NN + n)*CC + c] = m;
        #pragma unroll
        for (int t=0;t<3;t++){
            float val = v[3*i+t];
            int col = c*3 + t;
            xtb[((size_t)ib*COL + col)*KP + n] = __float2bfloat16(val);
            xvb[((size_t)ib*NN + n)*COL + col] = __float2bfloat16(val);
        }
    }
}

// fused: init state + all 4 GRU steps + edge projections. block per (b,n) row.
__global__ void k_gru_all(const float* __restrict__ stnf, const float* __restrict__ W_s2d,
                          const float* __restrict__ b_s2d, const float* __restrict__ inp,
                          const float* __restrict__ W_rz, const float* __restrict__ b_rz,
                          const float* __restrict__ W_h,  const float* __restrict__ b_h,
                          const float* __restrict__ Wc1,  const float* __restrict__ Wc2,
                          float* __restrict__ ga1, float* __restrict__ gb1,
                          float* __restrict__ ga2, float* __restrict__ gb2){
    int row = blockIdx.x;          // b*NN + n
    int n   = row % NN;
    int tid = threadIdx.x;         // 0..63
    __shared__ float cat[48];
    __shared__ float r_s[16], z_s[16], hs_s[16], st_s[16];
    if (tid < 16){
        float acc = b_s2d[tid];
        const float* srow = stnf + n*STF;
        #pragma unroll
        for (int k=0;k<STF;k++) acc += srow[k]*W_s2d[k*DHD + tid];
        st_s[tid] = acc;
    }
    __syncthreads();
    for (int i=0;i<NCH;i++){
        const float* ip = inp + ((size_t)i*BB*NN + row)*CC;
        if (tid < CC) cat[tid] = ip[tid];
        else if (tid < 48) cat[tid] = st_s[tid-32];
        __syncthreads();
        if (tid < 32){
            float acc = b_rz[tid];
            #pragma unroll
            for (int k=0;k<48;k++) acc += cat[k]*W_rz[k*32 + tid];
            float s = sigf(acc);
            if (tid < 16) r_s[tid] = s; else z_s[tid-16] = s;
        }
        __syncthreads();
        if (tid < 16) cat[32+tid] = r_s[tid]*st_s[tid];
        __syncthreads();
        if (tid < 16){
            float acc = b_h[tid];
            #pragma unroll
            for (int k=0;k<48;k++) acc += cat[k]*W_h[k*DHD + tid];
            float h_ = tanhf(acc);
            float z  = z_s[tid];
            float ns = z*st_s[tid] + (1.0f-z)*h_;
            st_s[tid] = ns;
            hs_s[tid] = fmaxf(ns, 0.0f);
        }
        __syncthreads();
        int j = tid & 15, which = tid >> 4;
        const float* W = (which < 2) ? Wc1 : Wc2;
        int off = (which & 1) ? 16*DHD : 0;
        float acc = 0.0f;
        #pragma unroll
        for (int k=0;k<16;k++) acc += hs_s[k]*W[off + k*DHD + j];
        float* dst = (which==0)? ga1 : (which==1)? gb1 : (which==2)? ga2 : gb2;
        dst[((size_t)i*BB*NN + row)*DHD + j] = acc;
        __syncthreads();
    }
}

#define AVT 8
// grid = NIB*38; adjb bf16 [ib][320][320], w in [300,320) zeroed (K-pad)
__global__ void k_adj(const float* __restrict__ ga1, const float* __restrict__ gb1,
                      const float* __restrict__ ga2, const float* __restrict__ gb2,
                      const float* __restrict__ bfc2_1, const float* __restrict__ wfc1_1, const float* __restrict__ bfc1_1,
                      const float* __restrict__ bfc2_2, const float* __restrict__ wfc1_2, const float* __restrict__ bfc1_2,
                      __hip_bfloat16* __restrict__ adjb){
    int tile = blockIdx.x % 38;
    int ib   = blockIdx.x / 38;
    int v0 = tile * AVT;
    int tid = threadIdx.x;  // 256
    __shared__ float a1[AVT][16], a2[AVT][16];
    __shared__ float w1[16], w2[16];
    if (tid < 16) w1[tid] = wfc1_1[tid];
    else if (tid < 32) w2[tid-16] = wfc1_2[tid-16];
    {
        int vl = tid >> 5, which = (tid >> 4) & 1, k = tid & 15;
        int v = v0 + vl;
        float val = 0.0f;
        if (v < NN)
            val = which ? (ga2[((size_t)ib*NN+v)*DHD + k] + bfc2_2[k])
                        : (ga1[((size_t)ib*NN+v)*DHD + k] + bfc2_1[k]);
        if (which) a2[vl][k] = val; else a1[vl][k] = val;
    }
    float B1 = bfc1_1[0], B2 = bfc1_2[0];
    __syncthreads();
    for (int w = tid; w < KP; w += 256){
        if (w < NN){
            const float4* p1 = (const float4*)(gb1 + ((size_t)ib*NN + w)*DHD);
            const float4* p2 = (const float4*)(gb2 + ((size_t)ib*NN + w)*DHD);
            float4 A[4], Bv[4];
            #pragma unroll
            for (int q=0;q<4;q++){ A[q]=p1[q]; Bv[q]=p2[q]; }
            const float* g1 = (const float*)A;
            const float* g2 = (const float*)Bv;
            for (int vl=0; vl<AVT; vl++){
                if (v0+vl >= NN) break;
                float s = B1, m = B2;
                #pragma unroll
                for (int k=0;k<16;k++){
                    s += fmaxf(a1[vl][k] + g1[k], 0.0f)*w1[k];
                    m += fmaxf(a2[vl][k] + g2[k], 0.0f)*w2[k];
                }
                adjb[((size_t)ib*KP + v0+vl)*KP + w] = __float2bfloat16(s * sigf(m));
            }
        } else {
            for (int vl=0; vl<AVT; vl++){
                if (v0+vl >= NN) break;
                adjb[((size_t)ib*KP + v0+vl)*KP + w] = __float2bfloat16(0.0f);
            }
        }
    }
}

// MFMA conv core: block = 4 waves, output tile 32 v-rows x 96 cols, K=320.
// A: adjb[ib][v][k] (row=l&15, k=8*(l>>4)+j) ; B: Hb[ib][col][k] ; D: col=l&15, row=(l>>4)*4+reg
__device__ __forceinline__ void conv_mfma_tile(const __hip_bfloat16* __restrict__ adjb,
                                               const __hip_bfloat16* __restrict__ Hb,
                                               int ib, int v0, int wave, int lane,
                                               f32x4& acc0, f32x4& acc1, f32x4& acc2){
    int l15 = lane & 15, lk = lane >> 4;
    int wrow = (wave & 1) * 16;
    int wcol = (wave >> 1) * 48;
    const short8* Ap  = (const short8*)(adjb + ((size_t)ib*KP + v0 + wrow + l15)*KP + 8*lk);
    const short8* Bp0 = (const short8*)(Hb   + ((size_t)ib*COL + wcol +  0 + l15)*KP + 8*lk);
    const short8* Bp1 = (const short8*)(Hb   + ((size_t)ib*COL + wcol + 16 + l15)*KP + 8*lk);
    const short8* Bp2 = (const short8*)(Hb   + ((size_t)ib*COL + wcol + 32 + l15)*KP + 8*lk);
    #pragma unroll 2
    for (int kk=0; kk<KP/32; kk++){
        short8 a = Ap[kk*4];
        acc0 = __builtin_amdgcn_mfma_f32_16x16x32_bf16(a, Bp0[kk*4], acc0, 0, 0, 0);
        acc1 = __builtin_amdgcn_mfma_f32_16x16x32_bf16(a, Bp1[kk*4], acc1, 0, 0, 0);
        acc2 = __builtin_amdgcn_mfma_f32_16x16x32_bf16(a, Bp2[kk*4], acc2, 0, 0, 0);
    }
}

// grid = NIB*10. h1 = 0.05*x + 0.95*(adj @ x); writes h1b [col][320] and h1vb [v][96]
__global__ __launch_bounds__(256) void k_conv1(const __hip_bfloat16* __restrict__ adjb,
                                               const __hip_bfloat16* __restrict__ xtb,
                                               const __hip_bfloat16* __restrict__ xvb,
                                               __hip_bfloat16* __restrict__ h1b,
                                               __hip_bfloat16* __restrict__ h1vb){
    int ib = blockIdx.x / 10;
    int v0 = (blockIdx.x % 10) * 32;
    int tid = threadIdx.x;
    int wave = tid >> 6, lane = tid & 63;
    int l15 = lane & 15, lk = lane >> 4;
    int wrow = (wave & 1) * 16;
    int wcol = (wave >> 1) * 48;
    __shared__ float hbuf[COL][33];
    f32x4 acc0 = {0.f,0.f,0.f,0.f}, acc1 = acc0, acc2 = acc0;
    conv_mfma_tile(adjb, xtb, ib, v0, wave, lane, acc0, acc1, acc2);
    f32x4 accs[3] = {acc0, acc1, acc2};
    #pragma unroll
    for (int t=0;t<3;t++){
        int col = wcol + t*16 + l15;
        #pragma unroll
        for (int r=0;r<4;r++){
            int vloc = wrow + lk*4 + r;
            int v = v0 + vloc;
            float xval = (v < NN) ? __bfloat162float(xvb[((size_t)ib*NN + v)*COL + col]) : 0.0f;
            hbuf[col][vloc] = ALPHAF*xval + (1.0f-ALPHAF)*accs[t][r];
        }
    }
    __syncthreads();
    for (int idx = tid; idx < COL*32; idx += 256){
        int col = idx >> 5, vloc = idx & 31;
        int v = v0 + vloc;
        if (v < NN)
            h1b[((size_t)ib*COL + col)*KP + v] = __float2bfloat16(hbuf[col][vloc]);
    }
    for (int idx = tid; idx < 32*COL; idx += 256){
        int vloc = idx / COL, col = idx % COL;
        int v = v0 + vloc;
        if (v < NN)
            h1vb[((size_t)ib*NN + v)*COL + col] = __float2bfloat16(hbuf[col][vloc]);
    }
}

// grid = NIB*10. h2 = 0.05*x + 0.95*(adj @ h1); MLP done as MFMA (12 tiles, K=96).
__global__ __launch_bounds__(256) void k_conv2_mlp(const __hip_bfloat16* __restrict__ adjb,
                                                   const __hip_bfloat16* __restrict__ h1b,
                                                   const __hip_bfloat16* __restrict__ xvb,
                                                   const __hip_bfloat16* __restrict__ h1vb,
                                                   const __hip_bfloat16* __restrict__ Wmb,
                                                   const float* __restrict__ bmlp,
                                                   float* __restrict__ out){
    int ib = blockIdx.x / 10;
    int v0 = (blockIdx.x % 10) * 32;
    int b  = ib % BB, chunk = ib / BB;
    int tid = threadIdx.x;
    int wave = tid >> 6, lane = tid & 63;
    int l15 = lane & 15, lk = lane >> 4;
    int wrow = (wave & 1) * 16;
    int wcol = (wave >> 1) * 48;
    __shared__ ushort_t hst[3][3][32][HS];   // [t][depth][v][c]  bf16 bits
    // stage h0 (x) and h1 into hst while conv MFMAs run
    for (int idx = tid; idx < 2*32*COL; idx += 256){
        int which = idx / (32*COL);
        int r     = idx % (32*COL);
        int vloc  = r / COL, col = r % COL;
        int v = v0 + vloc;
        int c = col/3, t = col%3;
        ushort_t val = 0;
        if (v < NN){
            const ushort_t* src = (const ushort_t*)(which ? h1vb : xvb);
            val = src[((size_t)ib*NN + v)*COL + col];
        }
        hst[t][which][vloc][c] = val;
    }
    f32x4 acc0 = {0.f,0.f,0.f,0.f}, acc1 = acc0, acc2 = acc0;
    conv_mfma_tile(adjb, h1b, ib, v0, wave, lane, acc0, acc1, acc2);
    f32x4 accs[3] = {acc0, acc1, acc2};
    // h2 into hst
    #pragma unroll
    for (int tt=0;tt<3;tt++){
        int col = wcol + tt*16 + l15;
        int c = col/3, t = col%3;
        #pragma unroll
        for (int r=0;r<4;r++){
            int vloc = wrow + lk*4 + r;
            int v = v0 + vloc;
            float val = 0.0f;
            if (v < NN){
                float xval = __bfloat162float(xvb[((size_t)ib*NN + v)*COL + col]);
                val = ALPHAF*xval + (1.0f-ALPHAF)*accs[tt][r];
            }
            __hip_bfloat16 bv = __float2bfloat16(val);
            hst[t][2][vloc][c] = *(ushort_t*)&bv;
        }
    }
    __syncthreads();
    // MLP MFMA: tiles (t, vt, ot); wave handles tile ids wave, wave+4, wave+8
    #pragma unroll
    for (int j=0;j<3;j++){
        int tile = wave + 4*j;
        int t  = tile >> 2;
        int vt = (tile & 3) >> 1;
        int ot = tile & 1;
        f32x4 acc = {0.f,0.f,0.f,0.f};
        #pragma unroll
        for (int d=0;d<3;d++){
            short8 a = *(const short8*)&hst[t][d][vt*16 + l15][8*lk];
            short8 bfr = *(const short8*)(Wmb + ((size_t)(ot*16 + l15))*COL + d*32 + 8*lk);
            acc = __builtin_amdgcn_mfma_f32_16x16x32_bf16(a, bfr, acc, 0, 0, 0);
        }
        int o = ot*16 + l15;
        float bias = bmlp[o];
        #pragma unroll
        for (int r=0;r<4;r++){
            int v = v0 + vt*16 + lk*4 + r;
            if (v < NN)
                out[(((size_t)b*COO + o)*NN + v)*TT + chunk*3 + t] = acc[r] + bias;
        }
    }
}

extern "C" void kernel_launch(void* const* d_in, const int* in_sizes, int n_in,
                              void* d_out, int out_size, void* d_ws, size_t ws_size,
                              hipStream_t stream){
    const float* x     = (const float*)d_in[0];
    const float* stnf  = (const float*)d_in[1];
    const float* W_s2d = (const float*)d_in[2];
    const float* b_s2d = (const float*)d_in[3];
    const float* W_rz  = (const float*)d_in[4];
    const float* b_rz  = (const float*)d_in[5];
    const float* W_h   = (const float*)d_in[6];
    const float* b_h   = (const float*)d_in[7];
    const float* Wc1f2 = (const float*)d_in[8];
    const float* bc1f2 = (const float*)d_in[9];
    const float* Wc1f1 = (const float*)d_in[10];
    const float* bc1f1 = (const float*)d_in[11];
    const float* Wc2f2 = (const float*)d_in[12];
    const float* bc2f2 = (const float*)d_in[13];
    const float* Wc2f1 = (const float*)d_in[14];
    const float* bc2f1 = (const float*)d_in[15];
    const float* W_mlp = (const float*)d_in[16];
    const float* b_mlp = (const float*)d_in[17];
    float* out = (float*)d_out;
    float* ws  = (float*)d_ws;

    float* inp = ws + O_INP;
    float* ga1 = ws + O_GA1;
    float* gb1 = ws + O_GB1;
    float* ga2 = ws + O_GA2;
    float* gb2 = ws + O_GB2;
    __hip_bfloat16* xvb  = (__hip_bfloat16*)(ws + O_XVB);
    __hip_bfloat16* adjb = (__hip_bfloat16*)(ws + O_ADJB);
    __hip_bfloat16* xtb  = (__hip_bfloat16*)(ws + O_XTB);
    __hip_bfloat16* h1b  = (__hip_bfloat16*)(ws + O_H1B);
    __hip_bfloat16* h1vb = (__hip_bfloat16*)(ws + O_H1VB);
    __hip_bfloat16* Wmb  = (__hip_bfloat16*)(ws + O_WMB);

    hipLaunchKernelGGL(k_prep, dim3(600), dim3(256), 0, stream, x, xtb, xvb, inp, h1b, W_mlp, Wmb);
    hipLaunchKernelGGL(k_gru_all, dim3(BB*NN), dim3(64), 0, stream,
                       stnf, W_s2d, b_s2d, inp, W_rz, b_rz, W_h, b_h, Wc1f2, Wc2f2,
                       ga1, gb1, ga2, gb2);
    hipLaunchKernelGGL(k_adj, dim3(NIB*38), dim3(256), 0, stream,
                       ga1, gb1, ga2, gb2,
                       bc1f2, Wc1f1, bc1f1, bc2f2, Wc2f1, bc2f1, adjb);
    hipLaunchKernelGGL(k_conv1, dim3(NIB*10), dim3(256), 0, stream,
                       adjb, xtb, xvb, h1b, h1vb);
    hipLaunchKernelGGL(k_conv2_mlp, dim3(NIB*10), dim3(256), 0, stream,
                       adjb, h1b, xvb, h1vb, Wmb, b_mlp, out);
}